// Round 1
// baseline (387.161 us; speedup 1.0000x reference)
//
#include <hip/hip_runtime.h>
#include <hip/hip_fp16.h>

#define M_TOK 16384
#define H_DIM 1024
#define F_DIM 4096

typedef __attribute__((ext_vector_type(4))) int int4v;

// ---------------- workspace layout (bytes) ----------------
static const size_t OFF_H2    = 0;                       // fp16 [M,F]  134,217,728
static const size_t OFF_Q2    = OFF_H2   + 134217728ULL; // int8 [M,F]   67,108,864
static const size_t OFF_XQ    = OFF_Q2   + 67108864ULL;  // int8 [M,H]   16,777,216
static const size_t OFF_WQU   = OFF_XQ   + 16777216ULL;  // int8 [F,H]    4,194,304
static const size_t OFF_WQD   = OFF_WQU  + 4194304ULL;   // int8 [H,F]    4,194,304
static const size_t OFF_DQX   = OFF_WQD  + 4194304ULL;   // f32 [M]          65,536
static const size_t OFF_S2    = OFF_DQX  + 65536ULL;     // f32 [M]          65,536
static const size_t OFF_DQ2   = OFF_S2   + 65536ULL;     // f32 [M]          65,536
static const size_t OFF_PMAX  = OFF_DQ2  + 65536ULL;     // f32 [64,M]    4,194,304
static const size_t OFF_WPART = OFF_PMAX + 4194304ULL;   // f32 [2048]        8,192
static const size_t OFF_WSC   = OFF_WPART+ 8192ULL;      // f32 [4]
static const size_t WS_NEEDED = OFF_WSC  + 16ULL;        // ~230.9 MB

__device__ __forceinline__ void ldg_lds16(const void* g, void* l) {
  __builtin_amdgcn_global_load_lds(
      (const __attribute__((address_space(1))) void*)g,
      (__attribute__((address_space(3))) void*)l, 16, 0, 0);
}

// ---------------- K1: |w| partial sums (deterministic) ----------------
__global__ __launch_bounds__(256) void k_wabs(const float* __restrict__ wu,
                                              const float* __restrict__ wd,
                                              float* __restrict__ part) {
  const int b = blockIdx.x;                 // 0..2047 (1024 per tensor)
  const float* w = (b < 1024) ? wu : wd;
  const int cb = b & 1023;
  const size_t base = (size_t)cb * 4096 + threadIdx.x * 4;
  float s = 0.0f;
#pragma unroll
  for (int it = 0; it < 4; ++it) {
    const float4 v = *(const float4*)(w + base + it * 1024);
    s += fabsf(v.x) + fabsf(v.y) + fabsf(v.z) + fabsf(v.w);
  }
#pragma unroll
  for (int sh = 32; sh; sh >>= 1) s += __shfl_xor(s, sh, 64);
  __shared__ float red[4];
  if ((threadIdx.x & 63) == 0) red[threadIdx.x >> 6] = s;
  __syncthreads();
  if (threadIdx.x == 0) part[b] = red[0] + red[1] + red[2] + red[3];
}

// ---------------- K2: finalize per-tensor scale ----------------
__global__ __launch_bounds__(256) void k_wscale(const float* __restrict__ part,
                                                float* __restrict__ wsc) {
  const int b = blockIdx.x;                 // 0: w_up, 1: w_down
  const float* p = part + b * 1024;
  float s = p[threadIdx.x] + p[threadIdx.x + 256] + p[threadIdx.x + 512] + p[threadIdx.x + 768];
#pragma unroll
  for (int sh = 32; sh; sh >>= 1) s += __shfl_xor(s, sh, 64);
  __shared__ float red[4];
  if ((threadIdx.x & 63) == 0) red[threadIdx.x >> 6] = s;
  __syncthreads();
  if (threadIdx.x == 0) {
    const float mean = (red[0] + red[1] + red[2] + red[3]) * (1.0f / 4194304.0f);
    const float c = fmaxf(mean, 1e-5f);
    wsc[b * 2]     = c;         // dequant factor (1/scale)
    wsc[b * 2 + 1] = 1.0f / c;  // scale
  }
}

// ---------------- K3: ternary-quantize both weights ----------------
__global__ __launch_bounds__(256) void k_wquant(const float* __restrict__ wu,
                                                const float* __restrict__ wd,
                                                char* __restrict__ qu,
                                                char* __restrict__ qd,
                                                const float* __restrict__ wsc) {
  const size_t t = (size_t)blockIdx.x * 256 + threadIdx.x;  // 0..2097151
  const float* w; char* q; float scale; size_t i;
  if (t < 1048576) { w = wu; q = qu; scale = wsc[1]; i = t * 4; }
  else             { w = wd; q = qd; scale = wsc[3]; i = (t - 1048576) * 4; }
  const float4 v = *(const float4*)(w + i);
  const int a = (int)rintf(fminf(fmaxf(v.x * scale, -1.0f), 1.0f));
  const int b = (int)rintf(fminf(fmaxf(v.y * scale, -1.0f), 1.0f));
  const int c = (int)rintf(fminf(fmaxf(v.z * scale, -1.0f), 1.0f));
  const int d = (int)rintf(fminf(fmaxf(v.w * scale, -1.0f), 1.0f));
  *(unsigned*)(q + i) = (a & 255) | ((b & 255) << 8) | ((c & 255) << 16) | ((d & 255) << 24);
}

// ---------------- K4: fused RMSNorm + act_quant ----------------
__global__ __launch_bounds__(256) void k_rmsnorm_quant(const float* __restrict__ x,
                                                       const float* __restrict__ nw,
                                                       char* __restrict__ xq,
                                                       float* __restrict__ dqx) {
  const int row = blockIdx.x;
  const int t = threadIdx.x;
  const float4 v = *(const float4*)(x + (size_t)row * H_DIM + t * 4);
  float ss = v.x * v.x + v.y * v.y + v.z * v.z + v.w * v.w;
#pragma unroll
  for (int sh = 32; sh; sh >>= 1) ss += __shfl_xor(ss, sh, 64);
  __shared__ float red[4];
  __shared__ float redm[4];
  if ((t & 63) == 0) red[t >> 6] = ss;
  __syncthreads();
  ss = red[0] + red[1] + red[2] + red[3];
  const float rinv = 1.0f / sqrtf(ss * (1.0f / 1024.0f) + 1e-6f);
  const float4 w4 = *(const float4*)(nw + t * 4);
  float4 n;
  n.x = v.x * rinv * w4.x;  n.y = v.y * rinv * w4.y;
  n.z = v.z * rinv * w4.z;  n.w = v.w * rinv * w4.w;
  float am = fmaxf(fmaxf(fabsf(n.x), fabsf(n.y)), fmaxf(fabsf(n.z), fabsf(n.w)));
#pragma unroll
  for (int sh = 32; sh; sh >>= 1) am = fmaxf(am, __shfl_xor(am, sh, 64));
  if ((t & 63) == 0) redm[t >> 6] = am;
  __syncthreads();
  am = fmaxf(fmaxf(redm[0], redm[1]), fmaxf(redm[2], redm[3]));
  am = fmaxf(am, 1e-5f);
  const float scale = 127.0f / am;
  const int qa = (int)rintf(fminf(fmaxf(n.x * scale, -128.0f), 127.0f));
  const int qb = (int)rintf(fminf(fmaxf(n.y * scale, -128.0f), 127.0f));
  const int qc = (int)rintf(fminf(fmaxf(n.z * scale, -128.0f), 127.0f));
  const int qd = (int)rintf(fminf(fmaxf(n.w * scale, -128.0f), 127.0f));
  *(unsigned*)(xq + (size_t)row * H_DIM + t * 4) =
      (qa & 255) | ((qb & 255) << 8) | ((qc & 255) << 16) | ((qd & 255) << 24);
  if (t == 0) dqx[row] = am * (1.0f / 127.0f);
}

// ---------------- shared int8 GEMM core (m97 recipe) ----------------
template <int LDA_, int LDB_, int KTILES>
__device__ __forceinline__ void gemm_core(const char* __restrict__ A,
                                          const char* __restrict__ B,
                                          int mBase, int nBase,
                                          char* As, char* Bs, int4v acc[4][4]) {
  const int t = threadIdx.x;
  const int lane = t & 63;
  const int wm = (t >> 6) & 1;
  const int wn = t >> 7;
  const int sRow = t >> 2;
  const int sCol = (t & 3) << 4;
  const char* Ag0 = A + (size_t)(mBase + sRow) * LDA_ + sCol;
  const char* Ag1 = A + (size_t)(mBase + 64 + sRow) * LDA_ + sCol;
  const char* Bg0 = B + (size_t)(nBase + sRow) * LDB_ + sCol;
  const char* Bg1 = B + (size_t)(nBase + 64 + sRow) * LDB_ + sCol;
  char* Al0 = As + t * 16;
  char* Al1 = As + 4096 + t * 16;
  char* Bl0 = Bs + t * 16;
  char* Bl1 = Bs + 4096 + t * 16;
  const int aOff = (wm * 64 + (lane & 15)) * 64 + ((lane >> 4) << 4);
  const int bOff = (wn * 64 + (lane & 15)) * 64 + ((lane >> 4) << 4);

  for (int kt = 0; kt < KTILES; ++kt) {
    __syncthreads();
    ldg_lds16(Ag0, Al0);
    ldg_lds16(Ag1, Al1);
    ldg_lds16(Bg0, Bl0);
    ldg_lds16(Bg1, Bl1);
    Ag0 += 64; Ag1 += 64; Bg0 += 64; Bg1 += 64;
    __syncthreads();
    int4v a[4], b[4];
#pragma unroll
    for (int i = 0; i < 4; ++i) a[i] = *(const int4v*)(As + aOff + i * 16 * 64);
#pragma unroll
    for (int j = 0; j < 4; ++j) b[j] = *(const int4v*)(Bs + bOff + j * 16 * 64);
#pragma unroll
    for (int i = 0; i < 4; ++i)
#pragma unroll
      for (int j = 0; j < 4; ++j)
        acc[i][j] = __builtin_amdgcn_mfma_i32_16x16x64_i8(a[i], b[j], acc[i][j], 0, 0, 0);
  }
}

// ---------------- K5: GEMM1 + relu^2 -> h2(fp16) + row-max partials ----------------
__global__ __launch_bounds__(256, 2) void k_gemm1(const char* __restrict__ xq,
                                                  const char* __restrict__ wq,
                                                  const float* __restrict__ wsc,
                                                  const float* __restrict__ dqx,
                                                  __half* __restrict__ h2,
                                                  float* __restrict__ pmax) {
  __shared__ char smem[16384];
  int4v acc[4][4];
#pragma unroll
  for (int i = 0; i < 4; ++i)
#pragma unroll
    for (int j = 0; j < 4; ++j) acc[i][j] = (int4v){0, 0, 0, 0};
  const int mBase = blockIdx.y * 128;
  const int nBase = blockIdx.x * 128;
  gemm_core<H_DIM, H_DIM, 16>(xq, wq, mBase, nBase, smem, smem + 8192, acc);

  const int t = threadIdx.x;
  const int lane = t & 63;
  const int wm = (t >> 6) & 1;
  const int wn = t >> 7;
  const float dqw = wsc[0];
#pragma unroll
  for (int i = 0; i < 4; ++i) {
    const int rbase = mBase + wm * 64 + i * 16 + ((lane >> 4) << 2);
    const float4 dq4 = *(const float4*)(dqx + rbase);
    const float* dqp = (const float*)&dq4;
    float rmax[4] = {0.0f, 0.0f, 0.0f, 0.0f};
#pragma unroll
    for (int j = 0; j < 4; ++j) {
      const int col = nBase + wn * 64 + j * 16 + (lane & 15);
#pragma unroll
      for (int r = 0; r < 4; ++r) {
        float v = (float)acc[i][j][r] * dqp[r] * dqw;
        v = fmaxf(v, 0.0f);
        v = v * v;
        const __half h = __float2half(v);
        h2[(size_t)(rbase + r) * F_DIM + col] = h;
        rmax[r] = fmaxf(rmax[r], __half2float(h));
      }
    }
#pragma unroll
    for (int s = 1; s < 16; s <<= 1) {
#pragma unroll
      for (int r = 0; r < 4; ++r) rmax[r] = fmaxf(rmax[r], __shfl_xor(rmax[r], s, 64));
    }
    if ((lane & 15) == 0) {
      const int nb2 = blockIdx.x * 2 + wn;
#pragma unroll
      for (int r = 0; r < 4; ++r) pmax[(size_t)nb2 * M_TOK + rbase + r] = rmax[r];
    }
  }
}

// ---------------- K5b: reduce row-max partials -> scale2/dq2 ----------------
__global__ __launch_bounds__(256) void k_rowred(const float* __restrict__ pmax,
                                                float* __restrict__ scale2,
                                                float* __restrict__ dq2) {
  const int row = blockIdx.x * 256 + threadIdx.x;
  float m = 0.0f;
#pragma unroll
  for (int i = 0; i < 64; ++i) m = fmaxf(m, pmax[(size_t)i * M_TOK + row]);
  m = fmaxf(m, 1e-5f);
  scale2[row] = 127.0f / m;
  dq2[row] = m * (1.0f / 127.0f);
}

// ---------------- K5c: quantize h2 -> q2 int8 ----------------
__global__ __launch_bounds__(256) void k_quant2(const __half* __restrict__ h2,
                                                const float* __restrict__ scale2,
                                                char* __restrict__ q2) {
  const size_t t = (size_t)blockIdx.x * 256 + threadIdx.x;
  const size_t i = t * 8;
  const int row = (int)(i >> 12);
  const float s = scale2[row];
  __half2 hh[4];
  *(float4*)hh = *(const float4*)(h2 + i);
  int q[8];
#pragma unroll
  for (int k = 0; k < 4; ++k) {
    const float lo = __low2float(hh[k]);
    const float hi = __high2float(hh[k]);
    q[2 * k]     = (int)rintf(fminf(lo * s, 127.0f));
    q[2 * k + 1] = (int)rintf(fminf(hi * s, 127.0f));
  }
  const unsigned u0 = (q[0] & 255) | ((q[1] & 255) << 8) | ((q[2] & 255) << 16) | ((q[3] & 255) << 24);
  const unsigned u1 = (q[4] & 255) | ((q[5] & 255) << 8) | ((q[6] & 255) << 16) | ((q[7] & 255) << 24);
  *(uint2*)(q2 + i) = make_uint2(u0, u1);
}

// ---------------- K6: GEMM2 + dequant + residual ----------------
__global__ __launch_bounds__(256, 2) void k_gemm2(const char* __restrict__ q2,
                                                  const char* __restrict__ wq,
                                                  const float* __restrict__ wsc,
                                                  const float* __restrict__ dq2,
                                                  const float* __restrict__ x,
                                                  float* __restrict__ out) {
  __shared__ char smem[16384];
  int4v acc[4][4];
#pragma unroll
  for (int i = 0; i < 4; ++i)
#pragma unroll
    for (int j = 0; j < 4; ++j) acc[i][j] = (int4v){0, 0, 0, 0};
  const int mBase = blockIdx.y * 128;
  const int nBase = blockIdx.x * 128;
  gemm_core<F_DIM, F_DIM, 64>(q2, wq, mBase, nBase, smem, smem + 8192, acc);

  const int t = threadIdx.x;
  const int lane = t & 63;
  const int wm = (t >> 6) & 1;
  const int wn = t >> 7;
  const float dqw = wsc[2];
#pragma unroll
  for (int i = 0; i < 4; ++i) {
    const int rbase = mBase + wm * 64 + i * 16 + ((lane >> 4) << 2);
    const float4 dq4 = *(const float4*)(dq2 + rbase);
    const float* dqp = (const float*)&dq4;
#pragma unroll
    for (int j = 0; j < 4; ++j) {
      const int col = nBase + wn * 64 + j * 16 + (lane & 15);
#pragma unroll
      for (int r = 0; r < 4; ++r) {
        const size_t idx = (size_t)(rbase + r) * H_DIM + col;
        out[idx] = (float)acc[i][j][r] * dqp[r] * dqw + x[idx];
      }
    }
  }
}

extern "C" void kernel_launch(void* const* d_in, const int* in_sizes, int n_in,
                              void* d_out, int out_size, void* d_ws, size_t ws_size,
                              hipStream_t stream) {
  const float* x  = (const float*)d_in[0];
  const float* nw = (const float*)d_in[1];
  const float* wu = (const float*)d_in[2];
  const float* wd = (const float*)d_in[3];
  float* out = (float*)d_out;
  char* ws = (char*)d_ws;
  if (ws_size < WS_NEEDED) return;  // workspace too small: leave output poisoned (diagnostic)

  __half* h2     = (__half*)(ws + OFF_H2);
  char* q2       = ws + OFF_Q2;
  char* xq       = ws + OFF_XQ;
  char* wqu      = ws + OFF_WQU;
  char* wqd      = ws + OFF_WQD;
  float* dqx     = (float*)(ws + OFF_DQX);
  float* scale2  = (float*)(ws + OFF_S2);
  float* dq2     = (float*)(ws + OFF_DQ2);
  float* pmax    = (float*)(ws + OFF_PMAX);
  float* wpart   = (float*)(ws + OFF_WPART);
  float* wsc     = (float*)(ws + OFF_WSC);

  k_wabs<<<2048, 256, 0, stream>>>(wu, wd, wpart);
  k_wscale<<<2, 256, 0, stream>>>(wpart, wsc);
  k_wquant<<<8192, 256, 0, stream>>>(wu, wd, wqu, wqd, wsc);
  k_rmsnorm_quant<<<M_TOK, 256, 0, stream>>>(x, nw, xq, dqx);
  k_gemm1<<<dim3(F_DIM / 128, M_TOK / 128), 256, 0, stream>>>(xq, wqu, wsc, dqx, h2, pmax);
  k_rowred<<<M_TOK / 256, 256, 0, stream>>>(pmax, scale2, dq2);
  k_quant2<<<(M_TOK * (F_DIM / 8)) / 256, 256, 0, stream>>>(h2, scale2, q2);
  k_gemm2<<<dim3(H_DIM / 128, M_TOK / 128), 256, 0, stream>>>(q2, wqd, wsc, dq2, x, out);
}

// Round 2
// 385.824 us; speedup vs baseline: 1.0035x; 1.0035x over previous
//
#include <hip/hip_runtime.h>
#include <hip/hip_fp16.h>

#define M_TOK 16384
#define H_DIM 1024
#define F_DIM 4096

typedef __attribute__((ext_vector_type(4))) int int4v;

// ---------------- workspace layout (bytes) ----------------
static const size_t OFF_H2    = 0;                       // fp16 [M,F]  134,217,728
static const size_t OFF_Q2    = OFF_H2   + 134217728ULL; // int8 [M,F]   67,108,864
static const size_t OFF_XQ    = OFF_Q2   + 67108864ULL;  // int8 [M,H]   16,777,216
static const size_t OFF_WQU   = OFF_XQ   + 16777216ULL;  // int8 [F,H]    4,194,304
static const size_t OFF_WQD   = OFF_WQU  + 4194304ULL;   // int8 [H,F]    4,194,304
static const size_t OFF_DQX   = OFF_WQD  + 4194304ULL;   // f32 [M]          65,536
static const size_t OFF_S2    = OFF_DQX  + 65536ULL;     // f32 [M]          65,536
static const size_t OFF_DQ2   = OFF_S2   + 65536ULL;     // f32 [M]          65,536
static const size_t OFF_PMAX  = OFF_DQ2  + 65536ULL;     // f32 [64,M]    4,194,304
static const size_t OFF_WPART = OFF_PMAX + 4194304ULL;   // f32 [2048]        8,192
static const size_t OFF_WSC   = OFF_WPART+ 8192ULL;      // f32 [4]
static const size_t WS_NEEDED = OFF_WSC  + 16ULL;        // ~230.9 MB

__device__ __forceinline__ void ldg_lds16(const void* g, void* l) {
  __builtin_amdgcn_global_load_lds(
      (const __attribute__((address_space(1))) void*)g,
      (__attribute__((address_space(3))) void*)l, 16, 0, 0);
}

// ---------------- K1: |w| partial sums (deterministic) ----------------
__global__ __launch_bounds__(256) void k_wabs(const float* __restrict__ wu,
                                              const float* __restrict__ wd,
                                              float* __restrict__ part) {
  const int b = blockIdx.x;                 // 0..2047 (1024 per tensor)
  const float* w = (b < 1024) ? wu : wd;
  const int cb = b & 1023;
  const size_t base = (size_t)cb * 4096 + threadIdx.x * 4;
  float s = 0.0f;
#pragma unroll
  for (int it = 0; it < 4; ++it) {
    const float4 v = *(const float4*)(w + base + it * 1024);
    s += fabsf(v.x) + fabsf(v.y) + fabsf(v.z) + fabsf(v.w);
  }
#pragma unroll
  for (int sh = 32; sh; sh >>= 1) s += __shfl_xor(s, sh, 64);
  __shared__ float red[4];
  if ((threadIdx.x & 63) == 0) red[threadIdx.x >> 6] = s;
  __syncthreads();
  if (threadIdx.x == 0) part[b] = red[0] + red[1] + red[2] + red[3];
}

// ---------------- K2: finalize per-tensor scale ----------------
__global__ __launch_bounds__(256) void k_wscale(const float* __restrict__ part,
                                                float* __restrict__ wsc) {
  const int b = blockIdx.x;                 // 0: w_up, 1: w_down
  const float* p = part + b * 1024;
  float s = p[threadIdx.x] + p[threadIdx.x + 256] + p[threadIdx.x + 512] + p[threadIdx.x + 768];
#pragma unroll
  for (int sh = 32; sh; sh >>= 1) s += __shfl_xor(s, sh, 64);
  __shared__ float red[4];
  if ((threadIdx.x & 63) == 0) red[threadIdx.x >> 6] = s;
  __syncthreads();
  if (threadIdx.x == 0) {
    const float mean = (red[0] + red[1] + red[2] + red[3]) * (1.0f / 4194304.0f);
    const float c = fmaxf(mean, 1e-5f);
    wsc[b * 2]     = c;         // dequant factor (1/scale)
    wsc[b * 2 + 1] = 1.0f / c;  // scale
  }
}

// ---------------- K3: ternary-quantize both weights ----------------
__global__ __launch_bounds__(256) void k_wquant(const float* __restrict__ wu,
                                                const float* __restrict__ wd,
                                                char* __restrict__ qu,
                                                char* __restrict__ qd,
                                                const float* __restrict__ wsc) {
  const size_t t = (size_t)blockIdx.x * 256 + threadIdx.x;  // 0..2097151
  const float* w; char* q; float scale; size_t i;
  if (t < 1048576) { w = wu; q = qu; scale = wsc[1]; i = t * 4; }
  else             { w = wd; q = qd; scale = wsc[3]; i = (t - 1048576) * 4; }
  const float4 v = *(const float4*)(w + i);
  const int a = (int)rintf(fminf(fmaxf(v.x * scale, -1.0f), 1.0f));
  const int b = (int)rintf(fminf(fmaxf(v.y * scale, -1.0f), 1.0f));
  const int c = (int)rintf(fminf(fmaxf(v.z * scale, -1.0f), 1.0f));
  const int d = (int)rintf(fminf(fmaxf(v.w * scale, -1.0f), 1.0f));
  *(unsigned*)(q + i) = (a & 255) | ((b & 255) << 8) | ((c & 255) << 16) | ((d & 255) << 24);
}

// ---------------- K4: fused RMSNorm + act_quant ----------------
__global__ __launch_bounds__(256) void k_rmsnorm_quant(const float* __restrict__ x,
                                                       const float* __restrict__ nw,
                                                       char* __restrict__ xq,
                                                       float* __restrict__ dqx) {
  const int row = blockIdx.x;
  const int t = threadIdx.x;
  const float4 v = *(const float4*)(x + (size_t)row * H_DIM + t * 4);
  float ss = v.x * v.x + v.y * v.y + v.z * v.z + v.w * v.w;
#pragma unroll
  for (int sh = 32; sh; sh >>= 1) ss += __shfl_xor(ss, sh, 64);
  __shared__ float red[4];
  __shared__ float redm[4];
  if ((t & 63) == 0) red[t >> 6] = ss;
  __syncthreads();
  ss = red[0] + red[1] + red[2] + red[3];
  const float rinv = 1.0f / sqrtf(ss * (1.0f / 1024.0f) + 1e-6f);
  const float4 w4 = *(const float4*)(nw + t * 4);
  float4 n;
  n.x = v.x * rinv * w4.x;  n.y = v.y * rinv * w4.y;
  n.z = v.z * rinv * w4.z;  n.w = v.w * rinv * w4.w;
  float am = fmaxf(fmaxf(fabsf(n.x), fabsf(n.y)), fmaxf(fabsf(n.z), fabsf(n.w)));
#pragma unroll
  for (int sh = 32; sh; sh >>= 1) am = fmaxf(am, __shfl_xor(am, sh, 64));
  if ((t & 63) == 0) redm[t >> 6] = am;
  __syncthreads();
  am = fmaxf(fmaxf(redm[0], redm[1]), fmaxf(redm[2], redm[3]));
  am = fmaxf(am, 1e-5f);
  const float scale = 127.0f / am;
  const int qa = (int)rintf(fminf(fmaxf(n.x * scale, -128.0f), 127.0f));
  const int qb = (int)rintf(fminf(fmaxf(n.y * scale, -128.0f), 127.0f));
  const int qc = (int)rintf(fminf(fmaxf(n.z * scale, -128.0f), 127.0f));
  const int qd = (int)rintf(fminf(fmaxf(n.w * scale, -128.0f), 127.0f));
  *(unsigned*)(xq + (size_t)row * H_DIM + t * 4) =
      (qa & 255) | ((qb & 255) << 8) | ((qc & 255) << 16) | ((qd & 255) << 24);
  if (t == 0) dqx[row] = am * (1.0f / 127.0f);
}

// ---------------- shared int8 GEMM core (m97 recipe + XOR bank swizzle) ----------------
// LDS slot (row r, seg s) holds global (r, s ^ ((r>>1)&3)); reads spread 16 lanes
// over all 8 bank-quads (2-way aliasing only, free per m136).
template <int LDA_, int LDB_, int KTILES>
__device__ __forceinline__ void gemm_core(const char* __restrict__ A,
                                          const char* __restrict__ B,
                                          int mBase, int nBase,
                                          char* As, char* Bs, int4v acc[4][4]) {
  const int t = threadIdx.x;
  const int lane = t & 63;
  const int wm = (t >> 6) & 1;
  const int wn = t >> 7;
  const int sRow = t >> 2;
  const int sSeg = (((t & 3) ^ ((t >> 3) & 3)) << 4);  // swizzled global col-seg
  const char* Ag0 = A + (size_t)(mBase + sRow) * LDA_ + sSeg;
  const char* Ag1 = A + (size_t)(mBase + 64 + sRow) * LDA_ + sSeg;
  const char* Bg0 = B + (size_t)(nBase + sRow) * LDB_ + sSeg;
  const char* Bg1 = B + (size_t)(nBase + 64 + sRow) * LDB_ + sSeg;
  char* Al0 = As + t * 16;
  char* Al1 = As + 4096 + t * 16;
  char* Bl0 = Bs + t * 16;
  char* Bl1 = Bs + 4096 + t * 16;
  const int q = lane >> 4;
  const int r0a = wm * 64 + (lane & 15);
  const int r0b = wn * 64 + (lane & 15);
  const int aOff = r0a * 64 + ((q ^ ((r0a >> 1) & 3)) << 4);
  const int bOff = r0b * 64 + ((q ^ ((r0b >> 1) & 3)) << 4);

  for (int kt = 0; kt < KTILES; ++kt) {
    __syncthreads();
    ldg_lds16(Ag0, Al0);
    ldg_lds16(Ag1, Al1);
    ldg_lds16(Bg0, Bl0);
    ldg_lds16(Bg1, Bl1);
    Ag0 += 64; Ag1 += 64; Bg0 += 64; Bg1 += 64;
    __syncthreads();
    int4v a[4], b[4];
#pragma unroll
    for (int i = 0; i < 4; ++i) a[i] = *(const int4v*)(As + aOff + i * 16 * 64);
#pragma unroll
    for (int j = 0; j < 4; ++j) b[j] = *(const int4v*)(Bs + bOff + j * 16 * 64);
#pragma unroll
    for (int i = 0; i < 4; ++i)
#pragma unroll
      for (int j = 0; j < 4; ++j)
        acc[i][j] = __builtin_amdgcn_mfma_i32_16x16x64_i8(a[i], b[j], acc[i][j], 0, 0, 0);
  }
}

// ---------------- K5: GEMM1 + relu^2 -> h2(fp16) + row-max partials ----------------
// grid: (x = m-blocks, y = n-blocks) — m-fastest for L2 B-reuse / single A fetch
__global__ __launch_bounds__(256, 2) void k_gemm1(const char* __restrict__ xq,
                                                  const char* __restrict__ wq,
                                                  const float* __restrict__ wsc,
                                                  const float* __restrict__ dqx,
                                                  __half* __restrict__ h2,
                                                  float* __restrict__ pmax) {
  __shared__ char smem[16384];
  int4v acc[4][4];
#pragma unroll
  for (int i = 0; i < 4; ++i)
#pragma unroll
    for (int j = 0; j < 4; ++j) acc[i][j] = (int4v){0, 0, 0, 0};
  const int mBase = blockIdx.x * 128;
  const int nBase = blockIdx.y * 128;
  gemm_core<H_DIM, H_DIM, 16>(xq, wq, mBase, nBase, smem, smem + 8192, acc);

  const int t = threadIdx.x;
  const int lane = t & 63;
  const int wm = (t >> 6) & 1;
  const int wn = t >> 7;
  const float dqw = wsc[0];
#pragma unroll
  for (int i = 0; i < 4; ++i) {
    const int rbase = mBase + wm * 64 + i * 16 + ((lane >> 4) << 2);
    const float4 dq4 = *(const float4*)(dqx + rbase);
    const float* dqp = (const float*)&dq4;
    float rmax[4] = {0.0f, 0.0f, 0.0f, 0.0f};
#pragma unroll
    for (int j = 0; j < 4; ++j) {
      const int col = nBase + wn * 64 + j * 16 + (lane & 15);
#pragma unroll
      for (int r = 0; r < 4; ++r) {
        float v = (float)acc[i][j][r] * dqp[r] * dqw;
        v = fmaxf(v, 0.0f);
        v = v * v;
        const __half h = __float2half(v);
        h2[(size_t)(rbase + r) * F_DIM + col] = h;
        rmax[r] = fmaxf(rmax[r], __half2float(h));
      }
    }
#pragma unroll
    for (int s = 1; s < 16; s <<= 1) {
#pragma unroll
      for (int r = 0; r < 4; ++r) rmax[r] = fmaxf(rmax[r], __shfl_xor(rmax[r], s, 64));
    }
    if ((lane & 15) == 0) {
      const int nb2 = blockIdx.y * 2 + wn;
#pragma unroll
      for (int r = 0; r < 4; ++r) pmax[(size_t)nb2 * M_TOK + rbase + r] = rmax[r];
    }
  }
}

// ---------------- K5b: reduce row-max partials -> scale2/dq2 ----------------
__global__ __launch_bounds__(256) void k_rowred(const float* __restrict__ pmax,
                                                float* __restrict__ scale2,
                                                float* __restrict__ dq2) {
  const int row = blockIdx.x * 256 + threadIdx.x;
  float m = 0.0f;
#pragma unroll
  for (int i = 0; i < 64; ++i) m = fmaxf(m, pmax[(size_t)i * M_TOK + row]);
  m = fmaxf(m, 1e-5f);
  scale2[row] = 127.0f / m;
  dq2[row] = m * (1.0f / 127.0f);
}

// ---------------- K5c: quantize h2 -> q2 int8 ----------------
__global__ __launch_bounds__(256) void k_quant2(const __half* __restrict__ h2,
                                                const float* __restrict__ scale2,
                                                char* __restrict__ q2) {
  const size_t t = (size_t)blockIdx.x * 256 + threadIdx.x;
  const size_t i = t * 8;
  const int row = (int)(i >> 12);
  const float s = scale2[row];
  __half2 hh[4];
  *(float4*)hh = *(const float4*)(h2 + i);
  int q[8];
#pragma unroll
  for (int k = 0; k < 4; ++k) {
    const float lo = __low2float(hh[k]);
    const float hi = __high2float(hh[k]);
    q[2 * k]     = (int)rintf(fminf(lo * s, 127.0f));
    q[2 * k + 1] = (int)rintf(fminf(hi * s, 127.0f));
  }
  const unsigned u0 = (q[0] & 255) | ((q[1] & 255) << 8) | ((q[2] & 255) << 16) | ((q[3] & 255) << 24);
  const unsigned u1 = (q[4] & 255) | ((q[5] & 255) << 8) | ((q[6] & 255) << 16) | ((q[7] & 255) << 24);
  *(uint2*)(q2 + i) = make_uint2(u0, u1);
}

// ---------------- K6: GEMM2 + dequant + residual ----------------
// grid: (x = m-blocks, y = n-blocks) — m-fastest
__global__ __launch_bounds__(256, 2) void k_gemm2(const char* __restrict__ q2,
                                                  const char* __restrict__ wq,
                                                  const float* __restrict__ wsc,
                                                  const float* __restrict__ dq2,
                                                  const float* __restrict__ x,
                                                  float* __restrict__ out) {
  __shared__ char smem[16384];
  int4v acc[4][4];
#pragma unroll
  for (int i = 0; i < 4; ++i)
#pragma unroll
    for (int j = 0; j < 4; ++j) acc[i][j] = (int4v){0, 0, 0, 0};
  const int mBase = blockIdx.x * 128;
  const int nBase = blockIdx.y * 128;
  gemm_core<F_DIM, F_DIM, 64>(q2, wq, mBase, nBase, smem, smem + 8192, acc);

  const int t = threadIdx.x;
  const int lane = t & 63;
  const int wm = (t >> 6) & 1;
  const int wn = t >> 7;
  const float dqw = wsc[2];
#pragma unroll
  for (int i = 0; i < 4; ++i) {
    const int rbase = mBase + wm * 64 + i * 16 + ((lane >> 4) << 2);
    const float4 dq4 = *(const float4*)(dq2 + rbase);
    const float* dqp = (const float*)&dq4;
#pragma unroll
    for (int j = 0; j < 4; ++j) {
      const int col = nBase + wn * 64 + j * 16 + (lane & 15);
#pragma unroll
      for (int r = 0; r < 4; ++r) {
        const size_t idx = (size_t)(rbase + r) * H_DIM + col;
        out[idx] = (float)acc[i][j][r] * dqp[r] * dqw + x[idx];
      }
    }
  }
}

extern "C" void kernel_launch(void* const* d_in, const int* in_sizes, int n_in,
                              void* d_out, int out_size, void* d_ws, size_t ws_size,
                              hipStream_t stream) {
  const float* x  = (const float*)d_in[0];
  const float* nw = (const float*)d_in[1];
  const float* wu = (const float*)d_in[2];
  const float* wd = (const float*)d_in[3];
  float* out = (float*)d_out;
  char* ws = (char*)d_ws;
  if (ws_size < WS_NEEDED) return;  // workspace too small: leave output poisoned (diagnostic)

  __half* h2     = (__half*)(ws + OFF_H2);
  char* q2       = ws + OFF_Q2;
  char* xq       = ws + OFF_XQ;
  char* wqu      = ws + OFF_WQU;
  char* wqd      = ws + OFF_WQD;
  float* dqx     = (float*)(ws + OFF_DQX);
  float* scale2  = (float*)(ws + OFF_S2);
  float* dq2     = (float*)(ws + OFF_DQ2);
  float* pmax    = (float*)(ws + OFF_PMAX);
  float* wpart   = (float*)(ws + OFF_WPART);
  float* wsc     = (float*)(ws + OFF_WSC);

  k_wabs<<<2048, 256, 0, stream>>>(wu, wd, wpart);
  k_wscale<<<2, 256, 0, stream>>>(wpart, wsc);
  k_wquant<<<8192, 256, 0, stream>>>(wu, wd, wqu, wqd, wsc);
  k_rmsnorm_quant<<<M_TOK, 256, 0, stream>>>(x, nw, xq, dqx);
  k_gemm1<<<dim3(M_TOK / 128, F_DIM / 128), 256, 0, stream>>>(xq, wqu, wsc, dqx, h2, pmax);
  k_rowred<<<M_TOK / 256, 256, 0, stream>>>(pmax, scale2, dq2);
  k_quant2<<<(M_TOK * (F_DIM / 8)) / 256, 256, 0, stream>>>(h2, scale2, q2);
  k_gemm2<<<dim3(M_TOK / 128, H_DIM / 128), 256, 0, stream>>>(q2, wqd, wsc, dq2, x, out);
}

// Round 3
// 361.351 us; speedup vs baseline: 1.0714x; 1.0677x over previous
//
#include <hip/hip_runtime.h>
#include <hip/hip_fp16.h>

#define M_TOK 16384
#define H_DIM 1024
#define F_DIM 4096

typedef __attribute__((ext_vector_type(4))) int int4v;

// ---------------- workspace layout (bytes) ----------------
static const size_t OFF_H2    = 0;                       // fp16 [M,F]  134,217,728
static const size_t OFF_Q2    = OFF_H2   + 134217728ULL; // int8 [M,F]   67,108,864
static const size_t OFF_XQ    = OFF_Q2   + 67108864ULL;  // int8 [M,H]   16,777,216
static const size_t OFF_WQU   = OFF_XQ   + 16777216ULL;  // int8 [F,H]    4,194,304
static const size_t OFF_WQD   = OFF_WQU  + 4194304ULL;   // int8 [H,F]    4,194,304
static const size_t OFF_DQX   = OFF_WQD  + 4194304ULL;   // f32 [M]          65,536
static const size_t OFF_DQ2   = OFF_DQX  + 65536ULL;     // f32 [M]          65,536
static const size_t OFF_PMAX  = OFF_DQ2  + 65536ULL;     // f32 [64,M]    4,194,304
static const size_t OFF_WPART = OFF_PMAX + 4194304ULL;   // f32 [2048]        8,192
static const size_t OFF_WSC   = OFF_WPART+ 8192ULL;      // f32 [4]
static const size_t WS_NEEDED = OFF_WSC  + 16ULL;

__device__ __forceinline__ void ldg_lds16(const void* g, void* l) {
  __builtin_amdgcn_global_load_lds(
      (const __attribute__((address_space(1))) void*)g,
      (__attribute__((address_space(3))) void*)l, 16, 0, 0);
}

// ---------------- K1: |w| partial sums (deterministic) ----------------
__global__ __launch_bounds__(256) void k_wabs(const float* __restrict__ wu,
                                              const float* __restrict__ wd,
                                              float* __restrict__ part) {
  const int b = blockIdx.x;                 // 0..2047 (1024 per tensor)
  const float* w = (b < 1024) ? wu : wd;
  const int cb = b & 1023;
  const size_t base = (size_t)cb * 4096 + threadIdx.x * 4;
  float s = 0.0f;
#pragma unroll
  for (int it = 0; it < 4; ++it) {
    const float4 v = *(const float4*)(w + base + it * 1024);
    s += fabsf(v.x) + fabsf(v.y) + fabsf(v.z) + fabsf(v.w);
  }
#pragma unroll
  for (int sh = 32; sh; sh >>= 1) s += __shfl_xor(s, sh, 64);
  __shared__ float red[4];
  if ((threadIdx.x & 63) == 0) red[threadIdx.x >> 6] = s;
  __syncthreads();
  if (threadIdx.x == 0) part[b] = red[0] + red[1] + red[2] + red[3];
}

// ---------------- K2: finalize per-tensor scale ----------------
__global__ __launch_bounds__(256) void k_wscale(const float* __restrict__ part,
                                                float* __restrict__ wsc) {
  const int b = blockIdx.x;                 // 0: w_up, 1: w_down
  const float* p = part + b * 1024;
  float s = p[threadIdx.x] + p[threadIdx.x + 256] + p[threadIdx.x + 512] + p[threadIdx.x + 768];
#pragma unroll
  for (int sh = 32; sh; sh >>= 1) s += __shfl_xor(s, sh, 64);
  __shared__ float red[4];
  if ((threadIdx.x & 63) == 0) red[threadIdx.x >> 6] = s;
  __syncthreads();
  if (threadIdx.x == 0) {
    const float mean = (red[0] + red[1] + red[2] + red[3]) * (1.0f / 4194304.0f);
    const float c = fmaxf(mean, 1e-5f);
    wsc[b * 2]     = c;         // dequant factor (1/scale)
    wsc[b * 2 + 1] = 1.0f / c;  // scale
  }
}

// ---------------- K3: ternary-quantize both weights ----------------
__global__ __launch_bounds__(256) void k_wquant(const float* __restrict__ wu,
                                                const float* __restrict__ wd,
                                                char* __restrict__ qu,
                                                char* __restrict__ qd,
                                                const float* __restrict__ wsc) {
  const size_t t = (size_t)blockIdx.x * 256 + threadIdx.x;  // 0..2097151
  const float* w; char* q; float scale; size_t i;
  if (t < 1048576) { w = wu; q = qu; scale = wsc[1]; i = t * 4; }
  else             { w = wd; q = qd; scale = wsc[3]; i = (t - 1048576) * 4; }
  const float4 v = *(const float4*)(w + i);
  const int a = (int)rintf(fminf(fmaxf(v.x * scale, -1.0f), 1.0f));
  const int b = (int)rintf(fminf(fmaxf(v.y * scale, -1.0f), 1.0f));
  const int c = (int)rintf(fminf(fmaxf(v.z * scale, -1.0f), 1.0f));
  const int d = (int)rintf(fminf(fmaxf(v.w * scale, -1.0f), 1.0f));
  *(unsigned*)(q + i) = (a & 255) | ((b & 255) << 8) | ((c & 255) << 16) | ((d & 255) << 24);
}

// ---------------- K4: fused RMSNorm + act_quant ----------------
__global__ __launch_bounds__(256) void k_rmsnorm_quant(const float* __restrict__ x,
                                                       const float* __restrict__ nw,
                                                       char* __restrict__ xq,
                                                       float* __restrict__ dqx) {
  const int row = blockIdx.x;
  const int t = threadIdx.x;
  const float4 v = *(const float4*)(x + (size_t)row * H_DIM + t * 4);
  float ss = v.x * v.x + v.y * v.y + v.z * v.z + v.w * v.w;
#pragma unroll
  for (int sh = 32; sh; sh >>= 1) ss += __shfl_xor(ss, sh, 64);
  __shared__ float red[4];
  __shared__ float redm[4];
  if ((t & 63) == 0) red[t >> 6] = ss;
  __syncthreads();
  ss = red[0] + red[1] + red[2] + red[3];
  const float rinv = 1.0f / sqrtf(ss * (1.0f / 1024.0f) + 1e-6f);
  const float4 w4 = *(const float4*)(nw + t * 4);
  float4 n;
  n.x = v.x * rinv * w4.x;  n.y = v.y * rinv * w4.y;
  n.z = v.z * rinv * w4.z;  n.w = v.w * rinv * w4.w;
  float am = fmaxf(fmaxf(fabsf(n.x), fabsf(n.y)), fmaxf(fabsf(n.z), fabsf(n.w)));
#pragma unroll
  for (int sh = 32; sh; sh >>= 1) am = fmaxf(am, __shfl_xor(am, sh, 64));
  if ((t & 63) == 0) redm[t >> 6] = am;
  __syncthreads();
  am = fmaxf(fmaxf(redm[0], redm[1]), fmaxf(redm[2], redm[3]));
  am = fmaxf(am, 1e-5f);
  const float scale = 127.0f / am;
  const int qa = (int)rintf(fminf(fmaxf(n.x * scale, -128.0f), 127.0f));
  const int qb = (int)rintf(fminf(fmaxf(n.y * scale, -128.0f), 127.0f));
  const int qc = (int)rintf(fminf(fmaxf(n.z * scale, -128.0f), 127.0f));
  const int qd = (int)rintf(fminf(fmaxf(n.w * scale, -128.0f), 127.0f));
  *(unsigned*)(xq + (size_t)row * H_DIM + t * 4) =
      (qa & 255) | ((qb & 255) << 8) | ((qc & 255) << 16) | ((qd & 255) << 24);
  if (t == 0) dqx[row] = am * (1.0f / 127.0f);
}

// ---------------- shared int8 GEMM core: 128x128 tile, BK=128 ----------------
// LDS tile: 128 rows x 128 B. Slot s (16B segs, s in 0..7) of row r holds global
// k-seg s ^ (r&7) -> fragment reads are 2-way bank aliasing (free, m136), and the
// staging DMA stays lane-contiguous (global_load_lds wave-uniform-base rule).
// 32 MFMA between each barrier pair (2x the BK=64 version) to amortize the
// vmcnt(0) drain at the barrier.
template <int LDA_, int LDB_, int KTILES>
__device__ __forceinline__ void gemm_core(const char* __restrict__ A,
                                          const char* __restrict__ B,
                                          int mBase, int nBase,
                                          char* As, char* Bs, int4v acc[4][4]) {
  const int t = threadIdx.x;
  const int lane = t & 63;
  const int wm = (t >> 6) & 1;
  const int wn = t >> 7;
  const int sRow = t >> 3;                      // 0..31
  const int sSeg = (t & 7) ^ (sRow & 7);        // swizzled global k-seg to fetch
  const char* Ag = A + (size_t)(mBase + sRow) * LDA_ + sSeg * 16;
  const char* Bg = B + (size_t)(nBase + sRow) * LDB_ + sSeg * 16;
  char* Al = As + t * 16;
  char* Bl = Bs + t * 16;
  const int q = lane >> 4;
  const int rA = wm * 64 + (lane & 15);
  const int rB = wn * 64 + (lane & 15);
  const int swA = rA & 7;                       // invariant under r += 16
  const int swB = rB & 7;

  for (int kt = 0; kt < KTILES; ++kt) {
    __syncthreads();
#pragma unroll
    for (int n = 0; n < 4; ++n) ldg_lds16(Ag + (size_t)n * 32 * LDA_, Al + n * 4096);
#pragma unroll
    for (int n = 0; n < 4; ++n) ldg_lds16(Bg + (size_t)n * 32 * LDB_, Bl + n * 4096);
    Ag += 128; Bg += 128;
    __syncthreads();
#pragma unroll
    for (int ks = 0; ks < 2; ++ks) {
      const int ao = (((ks * 4 + q) ^ swA) << 4);
      const int bo = (((ks * 4 + q) ^ swB) << 4);
      int4v a[4], b[4];
#pragma unroll
      for (int i = 0; i < 4; ++i) a[i] = *(const int4v*)(As + (rA + i * 16) * 128 + ao);
#pragma unroll
      for (int j = 0; j < 4; ++j) b[j] = *(const int4v*)(Bs + (rB + j * 16) * 128 + bo);
#pragma unroll
      for (int i = 0; i < 4; ++i)
#pragma unroll
        for (int j = 0; j < 4; ++j)
          acc[i][j] = __builtin_amdgcn_mfma_i32_16x16x64_i8(a[i], b[j], acc[i][j], 0, 0, 0);
    }
  }
}

// ---------------- K5: GEMM1 + relu^2 -> h2(fp16) + row-max partials ----------------
// grid: (x = m-blocks, y = n-blocks) — m-fastest for L2 B-reuse / single A fetch
__global__ __launch_bounds__(256, 2) void k_gemm1(const char* __restrict__ xq,
                                                  const char* __restrict__ wq,
                                                  const float* __restrict__ wsc,
                                                  const float* __restrict__ dqx,
                                                  __half* __restrict__ h2,
                                                  float* __restrict__ pmax) {
  __shared__ char smem[32768];
  int4v acc[4][4];
#pragma unroll
  for (int i = 0; i < 4; ++i)
#pragma unroll
    for (int j = 0; j < 4; ++j) acc[i][j] = (int4v){0, 0, 0, 0};
  const int mBase = blockIdx.x * 128;
  const int nBase = blockIdx.y * 128;
  gemm_core<H_DIM, H_DIM, 8>(xq, wq, mBase, nBase, smem, smem + 16384, acc);

  const int t = threadIdx.x;
  const int lane = t & 63;
  const int wm = (t >> 6) & 1;
  const int wn = t >> 7;
  const float dqw = wsc[0];
#pragma unroll
  for (int i = 0; i < 4; ++i) {
    const int rbase = mBase + wm * 64 + i * 16 + ((lane >> 4) << 2);
    const float4 dq4 = *(const float4*)(dqx + rbase);
    const float* dqp = (const float*)&dq4;
    float rmax[4] = {0.0f, 0.0f, 0.0f, 0.0f};
#pragma unroll
    for (int j = 0; j < 4; ++j) {
      const int col = nBase + wn * 64 + j * 16 + (lane & 15);
#pragma unroll
      for (int r = 0; r < 4; ++r) {
        float v = (float)acc[i][j][r] * dqp[r] * dqw;
        v = fmaxf(v, 0.0f);
        v = v * v;
        const __half h = __float2half(v);
        h2[(size_t)(rbase + r) * F_DIM + col] = h;
        rmax[r] = fmaxf(rmax[r], __half2float(h));
      }
    }
#pragma unroll
    for (int s = 1; s < 16; s <<= 1) {
#pragma unroll
      for (int r = 0; r < 4; ++r) rmax[r] = fmaxf(rmax[r], __shfl_xor(rmax[r], s, 64));
    }
    if ((lane & 15) == 0) {
      const int nb2 = blockIdx.y * 2 + wn;
#pragma unroll
      for (int r = 0; r < 4; ++r) pmax[(size_t)nb2 * M_TOK + rbase + r] = rmax[r];
    }
  }
}

// ---------------- K5b: fused row-max reduce + quantize h2 -> q2 ----------------
// one block per token row: reduce 64 pmax partials, then quantize 4096 fp16.
__global__ __launch_bounds__(256) void k_quant2(const __half* __restrict__ h2,
                                                const float* __restrict__ pmax,
                                                char* __restrict__ q2,
                                                float* __restrict__ dq2) {
  const int row = blockIdx.x;
  const int t = threadIdx.x;
  __shared__ float sm;
  if (t < 64) {
    float m = pmax[(size_t)t * M_TOK + row];
#pragma unroll
    for (int sh = 32; sh; sh >>= 1) m = fmaxf(m, __shfl_xor(m, sh, 64));
    if (t == 0) sm = fmaxf(m, 1e-5f);
  }
  __syncthreads();
  const float mx = sm;
  const float s = 127.0f / mx;
  if (t == 0) dq2[row] = mx * (1.0f / 127.0f);
  const size_t i = (size_t)row * F_DIM + t * 16;
  __half2 hh[8];
  *(float4*)(hh)     = *(const float4*)(h2 + i);
  *(float4*)(hh + 4) = *(const float4*)(h2 + i + 8);
  unsigned u[4];
#pragma unroll
  for (int k = 0; k < 4; ++k) {
    const int q0 = (int)rintf(fminf(__low2float(hh[2 * k]) * s, 127.0f));
    const int q1 = (int)rintf(fminf(__high2float(hh[2 * k]) * s, 127.0f));
    const int q2i = (int)rintf(fminf(__low2float(hh[2 * k + 1]) * s, 127.0f));
    const int q3 = (int)rintf(fminf(__high2float(hh[2 * k + 1]) * s, 127.0f));
    u[k] = (q0 & 255) | ((q1 & 255) << 8) | ((q2i & 255) << 16) | ((q3 & 255) << 24);
  }
  *(uint4*)(q2 + i) = make_uint4(u[0], u[1], u[2], u[3]);
}

// ---------------- K6: GEMM2 + dequant + residual ----------------
// grid: (x = m-blocks, y = n-blocks) — m-fastest
__global__ __launch_bounds__(256, 2) void k_gemm2(const char* __restrict__ q2,
                                                  const char* __restrict__ wq,
                                                  const float* __restrict__ wsc,
                                                  const float* __restrict__ dq2,
                                                  const float* __restrict__ x,
                                                  float* __restrict__ out) {
  __shared__ char smem[32768];
  int4v acc[4][4];
#pragma unroll
  for (int i = 0; i < 4; ++i)
#pragma unroll
    for (int j = 0; j < 4; ++j) acc[i][j] = (int4v){0, 0, 0, 0};
  const int mBase = blockIdx.x * 128;
  const int nBase = blockIdx.y * 128;
  gemm_core<F_DIM, F_DIM, 32>(q2, wq, mBase, nBase, smem, smem + 16384, acc);

  const int t = threadIdx.x;
  const int lane = t & 63;
  const int wm = (t >> 6) & 1;
  const int wn = t >> 7;
  const float dqw = wsc[2];
#pragma unroll
  for (int i = 0; i < 4; ++i) {
    const int rbase = mBase + wm * 64 + i * 16 + ((lane >> 4) << 2);
    const float4 dq4 = *(const float4*)(dq2 + rbase);
    const float* dqp = (const float*)&dq4;
#pragma unroll
    for (int j = 0; j < 4; ++j) {
      const int col = nBase + wn * 64 + j * 16 + (lane & 15);
#pragma unroll
      for (int r = 0; r < 4; ++r) {
        const size_t idx = (size_t)(rbase + r) * H_DIM + col;
        out[idx] = (float)acc[i][j][r] * dqp[r] * dqw + x[idx];
      }
    }
  }
}

extern "C" void kernel_launch(void* const* d_in, const int* in_sizes, int n_in,
                              void* d_out, int out_size, void* d_ws, size_t ws_size,
                              hipStream_t stream) {
  const float* x  = (const float*)d_in[0];
  const float* nw = (const float*)d_in[1];
  const float* wu = (const float*)d_in[2];
  const float* wd = (const float*)d_in[3];
  float* out = (float*)d_out;
  char* ws = (char*)d_ws;
  if (ws_size < WS_NEEDED) return;  // workspace too small: leave output poisoned (diagnostic)

  __half* h2     = (__half*)(ws + OFF_H2);
  char* q2       = ws + OFF_Q2;
  char* xq       = ws + OFF_XQ;
  char* wqu      = ws + OFF_WQU;
  char* wqd      = ws + OFF_WQD;
  float* dqx     = (float*)(ws + OFF_DQX);
  float* dq2     = (float*)(ws + OFF_DQ2);
  float* pmax    = (float*)(ws + OFF_PMAX);
  float* wpart   = (float*)(ws + OFF_WPART);
  float* wsc     = (float*)(ws + OFF_WSC);

  k_wabs<<<2048, 256, 0, stream>>>(wu, wd, wpart);
  k_wscale<<<2, 256, 0, stream>>>(wpart, wsc);
  k_wquant<<<8192, 256, 0, stream>>>(wu, wd, wqu, wqd, wsc);
  k_rmsnorm_quant<<<M_TOK, 256, 0, stream>>>(x, nw, xq, dqx);
  k_gemm1<<<dim3(M_TOK / 128, F_DIM / 128), 256, 0, stream>>>(xq, wqu, wsc, dqx, h2, pmax);
  k_quant2<<<M_TOK, 256, 0, stream>>>(h2, pmax, q2, dq2);
  k_gemm2<<<dim3(M_TOK / 128, H_DIM / 128), 256, 0, stream>>>(q2, wqd, wsc, dq2, x, out);
}